// Round 11
// baseline (240.641 us; speedup 1.0000x reference)
//
#include <hip/hip_runtime.h>
#include <hip/hip_bf16.h>

#define D 64
#define LOGB 7            // 128 nodes per bin-bucket
#define BNODES 128
#define NS 4              // feature slices
#define FS 16             // features per slice
#define GRPN 32           // nodes per k_bucket5 group
#define CH 1024           // record chunk in k_bucket5
#define SUBN 32           // (fallback k_bucket4)
#define CHUNK 1024        // (fallback k_bucket4)
#define TN 64             // nodes per transform block

__device__ __forceinline__ float blo(unsigned u) { return __uint_as_float(u << 16); }
__device__ __forceinline__ float bhi(unsigned u) { return __uint_as_float(u & 0xffff0000u); }
__device__ __forceinline__ ushort f2bfr(float x) {
    __hip_bfloat16 hb = __float2bfloat16(x);     // RNE
    return *reinterpret_cast<ushort*>(&hb);
}

// ---------------- transform: g = bf16(feat @ W); zeroes bcnt/gcnt ----------------
// sliced=1: g layout [slice][node][16]; sliced=0: row-major [node][64] (fallback)

__global__ __launch_bounds__(256) void k_transform4(
    const float* __restrict__ feat, const float* __restrict__ W,
    ushort* __restrict__ g, int n_nodes, int* __restrict__ bcnt, int nbkt,
    int* __restrict__ gcnt, int sliced)
{
    int gt = blockIdx.x * 256 + threadIdx.x;
    if (gt < nbkt) bcnt[gt] = 0;
    if (gcnt != nullptr && gt < NS) gcnt[gt] = 0;

    __shared__ float ft[D][TN];   // [k][node]
    __shared__ float Ws[D][D];    // [k][j]

    int t = threadIdx.x;
    int n0 = blockIdx.x * TN;

    {   // stage W, coalesced
        const float4* W4 = (const float4*)W;
        float4* Ws4 = (float4*)&Ws[0][0];
        #pragma unroll
        for (int i = 0; i < 4; ++i) Ws4[t + i * 256] = W4[t + i * 256];
    }
    {   // stage feat tile transposed
        const float4* f4 = (const float4*)feat;
        #pragma unroll
        for (int it = 0; it < 4; ++it) {
            int i = it * 256 + t;
            int r = i >> 4, c = i & 15;
            int node = n0 + r;
            float4 v = (node < n_nodes) ? f4[(size_t)node * 16 + c]
                                        : make_float4(0.f, 0.f, 0.f, 0.f);
            ft[4 * c + 0][r] = v.x;
            ft[4 * c + 1][r] = v.y;
            ft[4 * c + 2][r] = v.z;
            ft[4 * c + 3][r] = v.w;
        }
    }
    __syncthreads();

    int nq = t >> 4, cq = t & 15;
    int n4 = nq * 4, c4 = cq * 4;

    float4 a0 = make_float4(0.f, 0.f, 0.f, 0.f);
    float4 a1 = a0, a2 = a0, a3 = a0;

    #pragma unroll 16
    for (int k = 0; k < D; ++k) {
        float4 fv = *reinterpret_cast<const float4*>(&ft[k][n4]);
        float4 wv = *reinterpret_cast<const float4*>(&Ws[k][c4]);
        a0.x = fmaf(fv.x, wv.x, a0.x); a0.y = fmaf(fv.x, wv.y, a0.y);
        a0.z = fmaf(fv.x, wv.z, a0.z); a0.w = fmaf(fv.x, wv.w, a0.w);
        a1.x = fmaf(fv.y, wv.x, a1.x); a1.y = fmaf(fv.y, wv.y, a1.y);
        a1.z = fmaf(fv.y, wv.z, a1.z); a1.w = fmaf(fv.y, wv.w, a1.w);
        a2.x = fmaf(fv.z, wv.x, a2.x); a2.y = fmaf(fv.z, wv.y, a2.y);
        a2.z = fmaf(fv.z, wv.z, a2.z); a2.w = fmaf(fv.z, wv.w, a2.w);
        a3.x = fmaf(fv.w, wv.x, a3.x); a3.y = fmaf(fv.w, wv.y, a3.y);
        a3.z = fmaf(fv.w, wv.z, a3.z); a3.w = fmaf(fv.w, wv.w, a3.w);
    }

    float4 accs[4] = {a0, a1, a2, a3};
    #pragma unroll
    for (int i = 0; i < 4; ++i) {
        int node = n0 + n4 + i;
        if (node < n_nodes) {
            ushort4 o;
            o.x = f2bfr(accs[i].x);
            o.y = f2bfr(accs[i].y);
            o.z = f2bfr(accs[i].z);
            o.w = f2bfr(accs[i].w);
            size_t addr = sliced
                ? (((size_t)(c4 >> 4) * n_nodes + node) * 16 + (c4 & 15))
                : ((size_t)node * D + c4);
            *reinterpret_cast<ushort4*>(g + addr) = o;
        }
    }
}

// ---------------- bucket binning ----------------

__global__ __launch_bounds__(256) void k_bin_count(
    const int* __restrict__ dst, int* __restrict__ cnt, int n_edges, int nbkt)
{
    __shared__ int sc[1024];
    int t = threadIdx.x;
    for (int i = t; i < 1024; i += 256) sc[i] = 0;
    __syncthreads();
    int n4 = n_edges >> 2;
    const int4* d4 = (const int4*)dst;
    int stride = gridDim.x * 256;
    for (int i = blockIdx.x * 256 + t; i < n4; i += stride) {
        int4 d = d4[i];
        atomicAdd(&sc[d.x >> LOGB], 1);
        atomicAdd(&sc[d.y >> LOGB], 1);
        atomicAdd(&sc[d.z >> LOGB], 1);
        atomicAdd(&sc[d.w >> LOGB], 1);
    }
    if (blockIdx.x == 0 && t == 0)
        for (int e = n4 << 2; e < n_edges; ++e) atomicAdd(&cnt[dst[e] >> LOGB], 1);
    __syncthreads();
    for (int i = t; i < nbkt; i += 256) {
        int c = sc[i];
        if (c) atomicAdd(&cnt[i], c);
    }
}

__global__ __launch_bounds__(1024) void k_bin_scan(
    const int* __restrict__ cnt, int* __restrict__ base,
    int* __restrict__ cursor, int nbkt)
{
    int t = threadIdx.x;
    int v = (t < nbkt) ? cnt[t] : 0;
    int lane = t & 63;
    int incl = v;
    #pragma unroll
    for (int o = 1; o < 64; o <<= 1) {
        int u = __shfl_up(incl, o, 64);
        if (lane >= o) incl += u;
    }
    __shared__ int wtot[16];
    if (lane == 63) wtot[t >> 6] = incl;
    __syncthreads();
    int wpre = 0;
    int w = t >> 6;
    for (int i = 0; i < w; ++i) wpre += wtot[i];
    int excl = wpre + incl - v;
    if (t < nbkt) { base[t] = excl; cursor[t] = excl; }
    if (t == nbkt - 1) base[nbkt] = excl + v;
}

__global__ __launch_bounds__(256) void k_bin_scatter(
    const int* __restrict__ src, const int* __restrict__ dst,
    int* __restrict__ cursor, unsigned* __restrict__ packed,
    int n_edges, int sbits)
{
    __shared__ int s_cnt[1024];
    __shared__ int s_base[1024];
    __shared__ int s_gb[1024];
    __shared__ int wtot[4];
    __shared__ unsigned s_stage[4096];
    __shared__ int s_addr[4096];

    int t = threadIdx.x;
    int chbase = blockIdx.x * 4096;
    int count = n_edges - chbase;
    if (count > 4096) count = 4096;

    for (int i = t; i < 1024; i += 256) s_cnt[i] = 0;
    __syncthreads();

    #pragma unroll
    for (int k = 0; k < 16; ++k) {
        int i = t + k * 256;
        if (i < count) atomicAdd(&s_cnt[dst[chbase + i] >> LOGB], 1);
    }
    __syncthreads();

    int b4 = t * 4;
    int v0 = s_cnt[b4], v1 = s_cnt[b4 + 1], v2 = s_cnt[b4 + 2], v3 = s_cnt[b4 + 3];
    int ssum = v0 + v1 + v2 + v3;
    int lane = t & 63;
    int incl = ssum;
    #pragma unroll
    for (int o = 1; o < 64; o <<= 1) {
        int u = __shfl_up(incl, o, 64);
        if (lane >= o) incl += u;
    }
    if (lane == 63) wtot[t >> 6] = incl;
    __syncthreads();
    int wpre = 0;
    int w = t >> 6;
    for (int i = 0; i < w; ++i) wpre += wtot[i];
    int excl = wpre + incl - ssum;
    s_base[b4]     = excl;
    s_base[b4 + 1] = excl + v0;
    s_base[b4 + 2] = excl + v0 + v1;
    s_base[b4 + 3] = excl + v0 + v1 + v2;
    __syncthreads();

    for (int i = t; i < 1024; i += 256) {
        int c = s_cnt[i];
        s_gb[i] = c ? atomicAdd(&cursor[i], c) : 0;
    }
    __syncthreads();
    for (int i = t; i < 1024; i += 256) s_cnt[i] = s_base[i];
    __syncthreads();

    #pragma unroll
    for (int k = 0; k < 16; ++k) {
        int i = t + k * 256;
        if (i < count) {
            int e = chbase + i;
            int d = dst[e];
            int s = src[e];
            int bkt = d >> LOGB;
            int pos = atomicAdd(&s_cnt[bkt], 1);
            s_stage[pos] = ((unsigned)(d & (BNODES - 1)) << sbits) | (unsigned)s;
            s_addr[pos]  = s_gb[bkt] + (pos - s_base[bkt]);
        }
    }
    __syncthreads();

    #pragma unroll
    for (int k = 0; k < 16; ++k) {
        int i = t + k * 256;
        if (i < count) packed[s_addr[i]] = s_stage[i];
    }
}

// ---------------- k_sort128: per-bucket full node sort -> csr2 + noff ----------------
// One block per 128-node bucket. Hist + scan in LDS, then scatter srcs into
// node-sorted order. Writes land within the bucket's 8KB window -> L2 write-back.

__global__ __launch_bounds__(256) void k_sort128(
    const unsigned* __restrict__ packed,
    const int* __restrict__ bbase,
    int* __restrict__ csr2,
    int* __restrict__ noff,
    int n_nodes, int sbits)
{
    __shared__ int s_cnt[BNODES];
    __shared__ int s_off[BNODES + 1];

    int t = threadIdx.x;
    int b = blockIdx.x;
    int gb = bbase[b], cnt = bbase[b + 1] - gb;

    if (t < BNODES) s_cnt[t] = 0;
    __syncthreads();
    for (int i = t; i < cnt; i += 256)
        atomicAdd(&s_cnt[packed[gb + i] >> sbits], 1);
    __syncthreads();

    if (t < 64) {
        int v0 = s_cnt[2 * t], v1 = s_cnt[2 * t + 1];
        int s = v0 + v1, incl = s;
        #pragma unroll
        for (int o = 1; o < 64; o <<= 1) {
            int u = __shfl_up(incl, o, 64);
            if (t >= o) incl += u;
        }
        int excl = incl - s;
        s_off[2 * t] = excl;
        s_off[2 * t + 1] = excl + v0;
        if (t == 63) s_off[BNODES] = incl;
    }
    __syncthreads();

    if (t <= BNODES) {
        int node = b * BNODES + t;
        if (node <= n_nodes) noff[node] = gb + s_off[t];
    }
    if (t < BNODES) s_cnt[t] = s_off[t];
    __syncthreads();

    unsigned smask = (1u << sbits) - 1u;
    for (int i = t; i < cnt; i += 256) {
        unsigned v = packed[gb + i];
        int pos = atomicAdd(&s_cnt[v >> sbits], 1);
        csr2[gb + pos] = (int)(v & smask);
    }
}

// ---------------- k_bucket5: sliced, XCD-pinned gather + mean + epilogue ----------------
// grid = ngrp*NS. Each block claims (grp, slice) via XCC_ID-keyed work stealing,
// so every XCD gathers only its 3.2MB g-slice (L2-resident). 4-lane groups read
// uint2 (32B/record); segments delineated by noff (no in-block sort).

__global__ __launch_bounds__(256) void k_bucket5(
    const ushort* __restrict__ g,      // [NS][n_nodes][16]
    const float* __restrict__ bias,
    const int* __restrict__ noff,      // [n_nodes+1]
    const int* __restrict__ csr2,      // [E] srcs sorted by dst
    int* __restrict__ gcnt,            // [NS] job counters (zeroed by transform)
    float* __restrict__ out,
    int n_nodes, int ngrp)
{
    __shared__ int s_src[CH];
    __shared__ int s_noff[GRPN + 1];
    __shared__ int s_job[2];

    int t = threadIdx.x;
    if (t == 0) {
        unsigned xcc = __builtin_amdgcn_s_getreg(6164) & 7u;  // HW_REG_XCC_ID[3:0]
        int sl = (int)(xcc & 3u), grp = -1;
        for (int a = 0; a < NS && grp < 0; ++a) {
            int s2 = (sl + a) & 3;
            int v = atomicAdd(&gcnt[s2], 1);
            if (v < ngrp) { grp = v; sl = s2; }
        }
        s_job[0] = grp; s_job[1] = sl;
    }
    __syncthreads();
    int grp = s_job[0], sl = s_job[1];
    if (grp < 0) return;               // cannot happen (grid == total jobs); defensive
    int n0 = grp * GRPN;

    if (t <= GRPN) {
        int node = n0 + t;
        s_noff[t] = noff[node > n_nodes ? n_nodes : node];
    }
    __syncthreads();

    int lane = t & 63, wid = t >> 6;
    int q2 = lane >> 2, m2 = lane & 3;
    const ushort* gsl = g + ((size_t)sl * n_nodes) * 16 + m2 * 4;

    float4 acc[8];
    #pragma unroll
    for (int k = 0; k < 8; ++k) acc[k] = make_float4(0.f, 0.f, 0.f, 0.f);

    int beg = s_noff[0], end = s_noff[GRPN];
    for (int cb = beg; cb < end; cb += CH) {
        int ccnt = end - cb;
        if (ccnt > CH) ccnt = CH;
        __syncthreads();
        for (int i = t; i < ccnt; i += 256) s_src[i] = csr2[cb + i];
        __syncthreads();

        int ce = cb + ccnt;
        #pragma unroll
        for (int k = 0; k < 8; ++k) {
            int r = wid * 8 + k;
            int lo = s_noff[r], hi = s_noff[r + 1];
            if (lo < cb) lo = cb;
            if (hi > ce) hi = ce;
            float4 a = acc[k];
            for (int i = lo; i < hi; i += 32) {
                int i0 = i + q2, i1 = i0 + 16;
                bool p0 = i0 < hi, p1 = i1 < hi;
                int s0 = s_src[(p0 ? i0 : lo) - cb];
                int s1 = s_src[(p1 ? i1 : lo) - cb];
                uint2 u0 = *reinterpret_cast<const uint2*>(gsl + (size_t)s0 * 16);
                uint2 u1 = *reinterpret_cast<const uint2*>(gsl + (size_t)s1 * 16);
                a.x += p0 ? blo(u0.x) : 0.0f;  a.y += p0 ? bhi(u0.x) : 0.0f;
                a.z += p0 ? blo(u0.y) : 0.0f;  a.w += p0 ? bhi(u0.y) : 0.0f;
                a.x += p1 ? blo(u1.x) : 0.0f;  a.y += p1 ? bhi(u1.x) : 0.0f;
                a.z += p1 ? blo(u1.y) : 0.0f;  a.w += p1 ? bhi(u1.y) : 0.0f;
            }
            acc[k] = a;
        }
    }

    // epilogue: reduce across the 16 lane-groups, mean / deg-0 fallback, +bias, ReLU
    float4 bj = *reinterpret_cast<const float4*>(bias + sl * FS + m2 * 4);
    #pragma unroll
    for (int k = 0; k < 8; ++k) {
        float4 v = acc[k];
        v.x += __shfl_xor(v.x, 4, 64);  v.y += __shfl_xor(v.y, 4, 64);
        v.z += __shfl_xor(v.z, 4, 64);  v.w += __shfl_xor(v.w, 4, 64);
        v.x += __shfl_xor(v.x, 8, 64);  v.y += __shfl_xor(v.y, 8, 64);
        v.z += __shfl_xor(v.z, 8, 64);  v.w += __shfl_xor(v.w, 8, 64);
        v.x += __shfl_xor(v.x, 16, 64); v.y += __shfl_xor(v.y, 16, 64);
        v.z += __shfl_xor(v.z, 16, 64); v.w += __shfl_xor(v.w, 16, 64);
        v.x += __shfl_xor(v.x, 32, 64); v.y += __shfl_xor(v.y, 32, 64);
        v.z += __shfl_xor(v.z, 32, 64); v.w += __shfl_xor(v.w, 32, 64);
        if (q2 == k) {
            int r = wid * 8 + k;
            int node = n0 + r;
            if (node < n_nodes) {
                int dgt = s_noff[r + 1] - s_noff[r];
                float4 res;
                if (dgt > 0) {
                    float inv = 1.0f / (float)dgt;
                    res = make_float4(v.x * inv, v.y * inv, v.z * inv, v.w * inv);
                } else {
                    uint2 u = *reinterpret_cast<const uint2*>(gsl + (size_t)node * 16);
                    res = make_float4(blo(u.x), bhi(u.x), blo(u.y), bhi(u.y));
                }
                res.x = fmaxf(res.x + bj.x, 0.0f);
                res.y = fmaxf(res.y + bj.y, 0.0f);
                res.z = fmaxf(res.z + bj.z, 0.0f);
                res.w = fmaxf(res.w + bj.w, 0.0f);
                *reinterpret_cast<float4*>(out + (size_t)node * D + sl * FS + m2 * 4) = res;
            }
        }
    }
}

// ---------------- fallback: R10 path (row-major g, in-block sort) ----------------

__global__ __launch_bounds__(256) void k_bucket4(
    const ushort* __restrict__ g,
    const float* __restrict__ bias,
    const int* __restrict__ base,
    const unsigned* __restrict__ packed,
    float* __restrict__ out,
    int n_nodes, int sbits)
{
    __shared__ unsigned s_raw[CHUNK];
    __shared__ unsigned s_rec[CHUNK];
    __shared__ int s_cnt[SUBN];
    __shared__ int s_off[SUBN + 1];

    int t = threadIdx.x;
    int lane = t & 63;
    int wid  = t >> 6;
    int q = lane >> 4;
    int m = lane & 15;
    int bkt = blockIdx.x >> 2;
    int sub = blockIdx.x & 3;
    int gb = base[bkt], ge = base[bkt + 1];
    unsigned smask = (1u << sbits) - 1u;
    const ushort* gm = g + 4 * m;

    float4 acc[8];
    int degv[8];
    #pragma unroll
    for (int k = 0; k < 8; ++k) {
        acc[k] = make_float4(0.f, 0.f, 0.f, 0.f);
        degv[k] = 0;
    }

    for (int cb = gb; cb < ge; cb += CHUNK) {
        int cnt = ge - cb;
        if (cnt > CHUNK) cnt = CHUNK;
        __syncthreads();
        if (t < SUBN) s_cnt[t] = 0;
        for (int i = t; i < cnt; i += 256) s_raw[i] = packed[cb + i];
        __syncthreads();
        for (int i = t; i < cnt; i += 256) {
            unsigned key = s_raw[i] >> sbits;
            if ((int)(key >> 5) == sub) atomicAdd(&s_cnt[key & 31], 1);
        }
        __syncthreads();
        if (t < 32) {
            int v = s_cnt[t];
            int incl = v;
            #pragma unroll
            for (int o = 1; o < 32; o <<= 1) {
                int u = __shfl_up(incl, o, 64);
                if (t >= o) incl += u;
            }
            int excl = incl - v;
            s_off[t] = excl;
            s_cnt[t] = excl;
            if (t == 31) s_off[32] = incl;
        }
        __syncthreads();
        for (int i = t; i < cnt; i += 256) {
            unsigned v = s_raw[i];
            unsigned key = v >> sbits;
            if ((int)(key >> 5) == sub) {
                int pos = atomicAdd(&s_cnt[key & 31], 1);
                s_rec[pos] = v;
            }
        }
        __syncthreads();
        #pragma unroll
        for (int k = 0; k < 8; ++k) {
            int r = wid * 8 + k;
            int beg = s_off[r], end = s_off[r + 1];
            float4 a = acc[k];
            for (int i = beg; i < end; i += 16) {
                int i0 = i + q, i1 = i0 + 4, i2 = i0 + 8, i3 = i0 + 12;
                bool p0 = i0 < end, p1 = i1 < end, p2 = i2 < end, p3 = i3 < end;
                unsigned r0 = s_rec[p0 ? i0 : beg];
                unsigned r1 = s_rec[p1 ? i1 : beg];
                unsigned r2 = s_rec[p2 ? i2 : beg];
                unsigned r3 = s_rec[p3 ? i3 : beg];
                int s0 = (int)(r0 & smask), s1 = (int)(r1 & smask);
                int s2 = (int)(r2 & smask), s3 = (int)(r3 & smask);
                uint2 u0 = *reinterpret_cast<const uint2*>(gm + (size_t)s0 * D);
                uint2 u1 = *reinterpret_cast<const uint2*>(gm + (size_t)s1 * D);
                uint2 u2 = *reinterpret_cast<const uint2*>(gm + (size_t)s2 * D);
                uint2 u3 = *reinterpret_cast<const uint2*>(gm + (size_t)s3 * D);
                a.x += p0 ? blo(u0.x) : 0.0f;  a.y += p0 ? bhi(u0.x) : 0.0f;
                a.z += p0 ? blo(u0.y) : 0.0f;  a.w += p0 ? bhi(u0.y) : 0.0f;
                a.x += p1 ? blo(u1.x) : 0.0f;  a.y += p1 ? bhi(u1.x) : 0.0f;
                a.z += p1 ? blo(u1.y) : 0.0f;  a.w += p1 ? bhi(u1.y) : 0.0f;
                a.x += p2 ? blo(u2.x) : 0.0f;  a.y += p2 ? bhi(u2.x) : 0.0f;
                a.z += p2 ? blo(u2.y) : 0.0f;  a.w += p2 ? bhi(u2.y) : 0.0f;
                a.x += p3 ? blo(u3.x) : 0.0f;  a.y += p3 ? bhi(u3.x) : 0.0f;
                a.z += p3 ? blo(u3.y) : 0.0f;  a.w += p3 ? bhi(u3.y) : 0.0f;
            }
            acc[k] = a;
            degv[k] += end - beg;
        }
    }

    float4 bj = *reinterpret_cast<const float4*>(bias + 4 * m);
    int n0 = (bkt << LOGB) + sub * SUBN;
    #pragma unroll
    for (int k = 0; k < 8; ++k) {
        float4 v = acc[k];
        v.x += __shfl_xor(v.x, 16, 64);
        v.y += __shfl_xor(v.y, 16, 64);
        v.z += __shfl_xor(v.z, 16, 64);
        v.w += __shfl_xor(v.w, 16, 64);
        v.x += __shfl_xor(v.x, 32, 64);
        v.y += __shfl_xor(v.y, 32, 64);
        v.z += __shfl_xor(v.z, 32, 64);
        v.w += __shfl_xor(v.w, 32, 64);
        if ((k & 3) == q) {
            int node = n0 + wid * 8 + k;
            if (node < n_nodes) {
                int dgt = degv[k];
                float4 res;
                if (dgt > 0) {
                    float inv = 1.0f / (float)dgt;
                    res = make_float4(v.x * inv, v.y * inv, v.z * inv, v.w * inv);
                } else {
                    uint2 u = *reinterpret_cast<const uint2*>(gm + (size_t)node * D);
                    res = make_float4(blo(u.x), bhi(u.x), blo(u.y), bhi(u.y));
                }
                res.x = fmaxf(res.x + bj.x, 0.0f);
                res.y = fmaxf(res.y + bj.y, 0.0f);
                res.z = fmaxf(res.z + bj.z, 0.0f);
                res.w = fmaxf(res.w + bj.w, 0.0f);
                *reinterpret_cast<float4*>(out + (size_t)node * D + 4 * m) = res;
            }
        }
    }
}

// ---------------- host ----------------

extern "C" void kernel_launch(void* const* d_in, const int* in_sizes, int n_in,
                              void* d_out, int out_size, void* d_ws, size_t ws_size,
                              hipStream_t stream)
{
    const float* feat = (const float*)d_in[0];
    const int*   src  = (const int*)d_in[1];
    const int*   dst  = (const int*)d_in[2];
    const float* W    = (const float*)d_in[3];
    const float* b    = (const float*)d_in[4];
    float* out = (float*)d_out;

    int n_nodes = in_sizes[0] / D;
    int n_edges = in_sizes[1];
    int nbkt = (n_nodes + BNODES - 1) >> LOGB;
    int ngrp = (n_nodes + GRPN - 1) / GRPN;

    int sbits = 1;
    while ((1 << sbits) < n_nodes && sbits < 25) sbits++;

    // new ws layout:
    //   bbase[nbkt+1] | bcnt[nbkt] | bcursor[nbkt] | gcnt[NS] | noff[N+1]
    //   | packed[E] u32 | csr2[E] int | g4[NS*N*16] ushort
    size_t base_off   = 0;
    size_t cnt_off    = (((size_t)(nbkt + 1) * 4) + 63) & ~(size_t)63;
    size_t cursor_off = (cnt_off + (size_t)nbkt * 4 + 63) & ~(size_t)63;
    size_t gcnt_off   = (cursor_off + (size_t)nbkt * 4 + 63) & ~(size_t)63;
    size_t noff_off   = (gcnt_off + NS * 4 + 63) & ~(size_t)63;
    size_t packed_off = (noff_off + ((size_t)n_nodes + 1) * 4 + 63) & ~(size_t)63;
    size_t csr2_off   = (packed_off + (size_t)n_edges * 4 + 63) & ~(size_t)63;
    size_t g_off      = (csr2_off + (size_t)n_edges * 4 + 63) & ~(size_t)63;
    size_t need_new   = g_off + (size_t)NS * n_nodes * FS * 2;

    // old (R10 fallback) layout: bbase | bcnt | bcursor | packed | g_row
    size_t o_packed_off = gcnt_off;   // reuse region
    size_t o_g_off      = (o_packed_off + (size_t)n_edges * 4 + 63) & ~(size_t)63;
    size_t need_old     = o_g_off + (size_t)n_nodes * D * 2;

    bool common_ok = (nbkt <= 1024) && (sbits + LOGB <= 32) &&
                     ((1 << sbits) >= n_nodes);
    char* ws = (char*)d_ws;
    int tblk = (n_nodes + TN - 1) / TN;
    int nblk = (n_edges + 4095) / 4096;

    if (common_ok && ws_size >= need_new) {
        int* bbase   = (int*)(ws + base_off);
        int* bcnt    = (int*)(ws + cnt_off);
        int* bcursor = (int*)(ws + cursor_off);
        int* gcnt    = (int*)(ws + gcnt_off);
        int* noff    = (int*)(ws + noff_off);
        unsigned* packed = (unsigned*)(ws + packed_off);
        int* csr2    = (int*)(ws + csr2_off);
        ushort* g    = (ushort*)(ws + g_off);

        k_transform4<<<tblk, 256, 0, stream>>>(feat, W, g, n_nodes,
                                               bcnt, nbkt, gcnt, 1);
        k_bin_count<<<512, 256, 0, stream>>>(dst, bcnt, n_edges, nbkt);
        k_bin_scan<<<1, 1024, 0, stream>>>(bcnt, bbase, bcursor, nbkt);
        k_bin_scatter<<<nblk, 256, 0, stream>>>(src, dst, bcursor, packed,
                                                n_edges, sbits);
        k_sort128<<<nbkt, 256, 0, stream>>>(packed, bbase, csr2, noff,
                                            n_nodes, sbits);
        k_bucket5<<<ngrp * NS, 256, 0, stream>>>(g, b, noff, csr2, gcnt, out,
                                                 n_nodes, ngrp);
    } else if (common_ok && ws_size >= need_old) {
        int* bbase   = (int*)(ws + base_off);
        int* bcnt    = (int*)(ws + cnt_off);
        int* bcursor = (int*)(ws + cursor_off);
        unsigned* packed = (unsigned*)(ws + o_packed_off);
        ushort* g    = (ushort*)(ws + o_g_off);

        k_transform4<<<tblk, 256, 0, stream>>>(feat, W, g, n_nodes,
                                               bcnt, nbkt, nullptr, 0);
        k_bin_count<<<512, 256, 0, stream>>>(dst, bcnt, n_edges, nbkt);
        k_bin_scan<<<1, 1024, 0, stream>>>(bcnt, bbase, bcursor, nbkt);
        k_bin_scatter<<<nblk, 256, 0, stream>>>(src, dst, bcursor, packed,
                                                n_edges, sbits);
        k_bucket4<<<nbkt * 4, 256, 0, stream>>>(g, b, bbase, packed, out,
                                                n_nodes, sbits);
    }
}

// Round 12
// 101.082 us; speedup vs baseline: 2.3806x; 2.3806x over previous
//
#include <hip/hip_runtime.h>
#include <hip/hip_bf16.h>

#define D 64
#define LOGB 7            // 128 nodes per bin-bucket
#define BNODES 128
#define GRP6 32           // nodes per k_bucket6 block
#define CH6 1024          // record chunk in k_bucket6
#define SUBN 32           // (fallback k_bucket4)
#define CHUNK 1024        // (fallback k_bucket4)
#define TN 64             // nodes per transform block

__device__ __forceinline__ float blo(unsigned u) { return __uint_as_float(u << 16); }
__device__ __forceinline__ float bhi(unsigned u) { return __uint_as_float(u & 0xffff0000u); }
__device__ __forceinline__ ushort f2bfr(float x) {
    __hip_bfloat16 hb = __float2bfloat16(x);     // RNE
    return *reinterpret_cast<ushort*>(&hb);
}

// ---------------- transform: g = bf16(feat @ W) row-major [(N+1)][64]
//   + zero sentinel row N + fused dst-histogram (blocks < hb). bcnt pre-zeroed.

__global__ __launch_bounds__(256) void k_transform5(
    const float* __restrict__ feat, const float* __restrict__ W,
    ushort* __restrict__ g, int n_nodes,
    const int* __restrict__ dst, int n_edges,
    int* __restrict__ bcnt, int nbkt, int hb)
{
    __shared__ float ft[D][TN];   // [k][node]
    __shared__ float Ws[D][D];    // [k][j]
    __shared__ int sc[1024];

    int t = threadIdx.x;
    int n0 = blockIdx.x * TN;

    // zero sentinel row (row n_nodes)
    if (blockIdx.x == 0 && t < 64) g[(size_t)n_nodes * D + t] = 0;

    {   // stage W, coalesced
        const float4* W4 = (const float4*)W;
        float4* Ws4 = (float4*)&Ws[0][0];
        #pragma unroll
        for (int i = 0; i < 4; ++i) Ws4[t + i * 256] = W4[t + i * 256];
    }
    {   // stage feat tile transposed
        const float4* f4 = (const float4*)feat;
        #pragma unroll
        for (int it = 0; it < 4; ++it) {
            int i = it * 256 + t;
            int r = i >> 4, c = i & 15;
            int node = n0 + r;
            float4 v = (node < n_nodes) ? f4[(size_t)node * 16 + c]
                                        : make_float4(0.f, 0.f, 0.f, 0.f);
            ft[4 * c + 0][r] = v.x;
            ft[4 * c + 1][r] = v.y;
            ft[4 * c + 2][r] = v.z;
            ft[4 * c + 3][r] = v.w;
        }
    }
    __syncthreads();

    int nq = t >> 4, cq = t & 15;
    int n4 = nq * 4, c4 = cq * 4;

    float4 a0 = make_float4(0.f, 0.f, 0.f, 0.f);
    float4 a1 = a0, a2 = a0, a3 = a0;

    #pragma unroll 16
    for (int k = 0; k < D; ++k) {
        float4 fv = *reinterpret_cast<const float4*>(&ft[k][n4]);
        float4 wv = *reinterpret_cast<const float4*>(&Ws[k][c4]);
        a0.x = fmaf(fv.x, wv.x, a0.x); a0.y = fmaf(fv.x, wv.y, a0.y);
        a0.z = fmaf(fv.x, wv.z, a0.z); a0.w = fmaf(fv.x, wv.w, a0.w);
        a1.x = fmaf(fv.y, wv.x, a1.x); a1.y = fmaf(fv.y, wv.y, a1.y);
        a1.z = fmaf(fv.y, wv.z, a1.z); a1.w = fmaf(fv.y, wv.w, a1.w);
        a2.x = fmaf(fv.z, wv.x, a2.x); a2.y = fmaf(fv.z, wv.y, a2.y);
        a2.z = fmaf(fv.z, wv.z, a2.z); a2.w = fmaf(fv.z, wv.w, a2.w);
        a3.x = fmaf(fv.w, wv.x, a3.x); a3.y = fmaf(fv.w, wv.y, a3.y);
        a3.z = fmaf(fv.w, wv.z, a3.z); a3.w = fmaf(fv.w, wv.w, a3.w);
    }

    float4 accs[4] = {a0, a1, a2, a3};
    #pragma unroll
    for (int i = 0; i < 4; ++i) {
        int node = n0 + n4 + i;
        if (node < n_nodes) {
            ushort4 o;
            o.x = f2bfr(accs[i].x);
            o.y = f2bfr(accs[i].y);
            o.z = f2bfr(accs[i].z);
            o.w = f2bfr(accs[i].w);
            *reinterpret_cast<ushort4*>(g + (size_t)node * D + c4) = o;
        }
    }

    // fused dst-histogram: blocks [0, hb), 16 int4 per thread, LDS-reduced
    if (blockIdx.x < (unsigned)hb) {
        for (int i = t; i < 1024; i += 256) sc[i] = 0;
        __syncthreads();
        int n4e = n_edges >> 2;
        const int4* d4 = (const int4*)dst;
        int base = blockIdx.x * 4096;
        #pragma unroll
        for (int k2 = 0; k2 < 16; ++k2) {
            int i = base + k2 * 256 + t;
            if (i < n4e) {
                int4 d = d4[i];
                atomicAdd(&sc[d.x >> LOGB], 1);
                atomicAdd(&sc[d.y >> LOGB], 1);
                atomicAdd(&sc[d.z >> LOGB], 1);
                atomicAdd(&sc[d.w >> LOGB], 1);
            }
        }
        if (blockIdx.x == 0 && t == 0)
            for (int e = n4e << 2; e < n_edges; ++e)
                atomicAdd(&bcnt[dst[e] >> LOGB], 1);
        __syncthreads();
        for (int i = t; i < nbkt; i += 256) {
            int c = sc[i];
            if (c) atomicAdd(&bcnt[i], c);
        }
    }
}

// ---------------- standalone count (used only if hb > tblk) ----------------

__global__ __launch_bounds__(256) void k_bin_count(
    const int* __restrict__ dst, int* __restrict__ cnt, int n_edges, int nbkt)
{
    __shared__ int sc[1024];
    int t = threadIdx.x;
    for (int i = t; i < 1024; i += 256) sc[i] = 0;
    __syncthreads();
    int n4 = n_edges >> 2;
    const int4* d4 = (const int4*)dst;
    int stride = gridDim.x * 256;
    for (int i = blockIdx.x * 256 + t; i < n4; i += stride) {
        int4 d = d4[i];
        atomicAdd(&sc[d.x >> LOGB], 1);
        atomicAdd(&sc[d.y >> LOGB], 1);
        atomicAdd(&sc[d.z >> LOGB], 1);
        atomicAdd(&sc[d.w >> LOGB], 1);
    }
    if (blockIdx.x == 0 && t == 0)
        for (int e = n4 << 2; e < n_edges; ++e) atomicAdd(&cnt[dst[e] >> LOGB], 1);
    __syncthreads();
    for (int i = t; i < nbkt; i += 256) {
        int c = sc[i];
        if (c) atomicAdd(&cnt[i], c);
    }
}

__global__ __launch_bounds__(1024) void k_bin_scan(
    const int* __restrict__ cnt, int* __restrict__ base,
    int* __restrict__ cursor, int nbkt)
{
    int t = threadIdx.x;
    int v = (t < nbkt) ? cnt[t] : 0;
    int lane = t & 63;
    int incl = v;
    #pragma unroll
    for (int o = 1; o < 64; o <<= 1) {
        int u = __shfl_up(incl, o, 64);
        if (lane >= o) incl += u;
    }
    __shared__ int wtot[16];
    if (lane == 63) wtot[t >> 6] = incl;
    __syncthreads();
    int wpre = 0;
    int w = t >> 6;
    for (int i = 0; i < w; ++i) wpre += wtot[i];
    int excl = wpre + incl - v;
    if (t < nbkt) { base[t] = excl; cursor[t] = excl; }
    if (t == nbkt - 1) base[nbkt] = excl + v;
}

__global__ __launch_bounds__(256) void k_bin_scatter(
    const int* __restrict__ src, const int* __restrict__ dst,
    int* __restrict__ cursor, unsigned* __restrict__ packed,
    int n_edges, int sbits)
{
    __shared__ int s_cnt[1024];
    __shared__ int s_base[1024];
    __shared__ int s_gb[1024];
    __shared__ int wtot[4];
    __shared__ unsigned s_stage[4096];
    __shared__ int s_addr[4096];

    int t = threadIdx.x;
    int chbase = blockIdx.x * 4096;
    int count = n_edges - chbase;
    if (count > 4096) count = 4096;

    for (int i = t; i < 1024; i += 256) s_cnt[i] = 0;
    __syncthreads();

    #pragma unroll
    for (int k = 0; k < 16; ++k) {
        int i = t + k * 256;
        if (i < count) atomicAdd(&s_cnt[dst[chbase + i] >> LOGB], 1);
    }
    __syncthreads();

    int b4 = t * 4;
    int v0 = s_cnt[b4], v1 = s_cnt[b4 + 1], v2 = s_cnt[b4 + 2], v3 = s_cnt[b4 + 3];
    int ssum = v0 + v1 + v2 + v3;
    int lane = t & 63;
    int incl = ssum;
    #pragma unroll
    for (int o = 1; o < 64; o <<= 1) {
        int u = __shfl_up(incl, o, 64);
        if (lane >= o) incl += u;
    }
    if (lane == 63) wtot[t >> 6] = incl;
    __syncthreads();
    int wpre = 0;
    int w = t >> 6;
    for (int i = 0; i < w; ++i) wpre += wtot[i];
    int excl = wpre + incl - ssum;
    s_base[b4]     = excl;
    s_base[b4 + 1] = excl + v0;
    s_base[b4 + 2] = excl + v0 + v1;
    s_base[b4 + 3] = excl + v0 + v1 + v2;
    __syncthreads();

    for (int i = t; i < 1024; i += 256) {
        int c = s_cnt[i];
        s_gb[i] = c ? atomicAdd(&cursor[i], c) : 0;
    }
    __syncthreads();
    for (int i = t; i < 1024; i += 256) s_cnt[i] = s_base[i];
    __syncthreads();

    #pragma unroll
    for (int k = 0; k < 16; ++k) {
        int i = t + k * 256;
        if (i < count) {
            int e = chbase + i;
            int d = dst[e];
            int s = src[e];
            int bkt = d >> LOGB;
            int pos = atomicAdd(&s_cnt[bkt], 1);
            s_stage[pos] = ((unsigned)(d & (BNODES - 1)) << sbits) | (unsigned)s;
            s_addr[pos]  = s_gb[bkt] + (pos - s_base[bkt]);
        }
    }
    __syncthreads();

    #pragma unroll
    for (int k = 0; k < 16; ++k) {
        int i = t + k * 256;
        if (i < count) packed[s_addr[i]] = s_stage[i];
    }
}

// ---------------- k_sort128: per-bucket full node sort -> csr2 + noff ----------------

__global__ __launch_bounds__(256) void k_sort128(
    const unsigned* __restrict__ packed,
    const int* __restrict__ bbase,
    int* __restrict__ csr2,
    int* __restrict__ noff,
    int n_nodes, int sbits)
{
    __shared__ int s_cnt[BNODES];
    __shared__ int s_off[BNODES + 1];

    int t = threadIdx.x;
    int b = blockIdx.x;
    int gb = bbase[b], cnt = bbase[b + 1] - gb;

    if (t < BNODES) s_cnt[t] = 0;
    __syncthreads();
    for (int i = t; i < cnt; i += 256)
        atomicAdd(&s_cnt[packed[gb + i] >> sbits], 1);
    __syncthreads();

    if (t < 64) {
        int v0 = s_cnt[2 * t], v1 = s_cnt[2 * t + 1];
        int s = v0 + v1, incl = s;
        #pragma unroll
        for (int o = 1; o < 64; o <<= 1) {
            int u = __shfl_up(incl, o, 64);
            if (t >= o) incl += u;
        }
        int excl = incl - s;
        s_off[2 * t] = excl;
        s_off[2 * t + 1] = excl + v0;
        if (t == 63) s_off[BNODES] = incl;
    }
    __syncthreads();

    if (t <= BNODES) {
        int node = b * BNODES + t;
        if (node <= n_nodes) noff[node] = gb + s_off[t];
    }
    if (t < BNODES) s_cnt[t] = s_off[t];
    __syncthreads();

    unsigned smask = (1u << sbits) - 1u;
    for (int i = t; i < cnt; i += 256) {
        unsigned v = packed[gb + i];
        int pos = atomicAdd(&s_cnt[v >> sbits], 1);
        csr2[gb + pos] = (int)(v & smask);
    }
}

// ---------------- k_bucket6: 32-node blocks over globally-sorted csr2 ----------------
// Records staged once per block (own span only). 16-lane groups load 128B g rows;
// 4 records/instr x 4-deep = 16 gathers in flight/wave. OOB -> zero sentinel row.

__global__ __launch_bounds__(256) void k_bucket6(
    const ushort* __restrict__ g,      // [(N+1)][64], row N = zeros
    const float* __restrict__ bias,
    const int* __restrict__ noff,      // [N+1]
    const int* __restrict__ csr2,      // [E] srcs sorted by dst
    float* __restrict__ out, int n_nodes)
{
    __shared__ int s_src[CH6];
    __shared__ int s_noff[GRP6 + 1];

    int t = threadIdx.x;
    int n0 = blockIdx.x * GRP6;
    if (t <= GRP6) {
        int node = n0 + t;
        s_noff[t] = noff[node > n_nodes ? n_nodes : node];
    }
    __syncthreads();

    int lane = t & 63, wid = t >> 6;
    int q = lane >> 4;                 // record slot 0..3
    int m = lane & 15;                 // features 4m..4m+3
    const ushort* gm = g + 4 * m;

    float4 acc[8];
    #pragma unroll
    for (int k = 0; k < 8; ++k) acc[k] = make_float4(0.f, 0.f, 0.f, 0.f);

    int beg = s_noff[0], end = s_noff[GRP6];
    for (int cb = beg; cb < end; cb += CH6) {
        int ce = cb + CH6 < end ? cb + CH6 : end;
        __syncthreads();               // protect s_src from previous chunk
        for (int i = cb + t; i < ce; i += 256) s_src[i - cb] = csr2[i];
        __syncthreads();

        #pragma unroll
        for (int k = 0; k < 8; ++k) {
            int r = wid * 8 + k;
            int lo = s_noff[r], hi = s_noff[r + 1];
            if (lo < cb) lo = cb;
            if (hi > ce) hi = ce;
            float4 a = acc[k];
            for (int i = lo; i < hi; i += 16) {
                int i0 = i + q, i1 = i0 + 4, i2 = i0 + 8, i3 = i0 + 12;
                int s0 = (i0 < hi) ? s_src[i0 - cb] : n_nodes;
                int s1 = (i1 < hi) ? s_src[i1 - cb] : n_nodes;
                int s2 = (i2 < hi) ? s_src[i2 - cb] : n_nodes;
                int s3 = (i3 < hi) ? s_src[i3 - cb] : n_nodes;
                uint2 u0 = *reinterpret_cast<const uint2*>(gm + (size_t)s0 * D);
                uint2 u1 = *reinterpret_cast<const uint2*>(gm + (size_t)s1 * D);
                uint2 u2 = *reinterpret_cast<const uint2*>(gm + (size_t)s2 * D);
                uint2 u3 = *reinterpret_cast<const uint2*>(gm + (size_t)s3 * D);
                a.x += blo(u0.x); a.y += bhi(u0.x); a.z += blo(u0.y); a.w += bhi(u0.y);
                a.x += blo(u1.x); a.y += bhi(u1.x); a.z += blo(u1.y); a.w += bhi(u1.y);
                a.x += blo(u2.x); a.y += bhi(u2.x); a.z += blo(u2.y); a.w += bhi(u2.y);
                a.x += blo(u3.x); a.y += bhi(u3.x); a.z += blo(u3.y); a.w += bhi(u3.y);
            }
            acc[k] = a;
        }
    }

    // epilogue: reduce across record-slot groups, mean / deg-0 fallback, +bias, ReLU
    float4 bj = *reinterpret_cast<const float4*>(bias + 4 * m);
    #pragma unroll
    for (int k = 0; k < 8; ++k) {
        float4 v = acc[k];
        v.x += __shfl_xor(v.x, 16, 64);
        v.y += __shfl_xor(v.y, 16, 64);
        v.z += __shfl_xor(v.z, 16, 64);
        v.w += __shfl_xor(v.w, 16, 64);
        v.x += __shfl_xor(v.x, 32, 64);
        v.y += __shfl_xor(v.y, 32, 64);
        v.z += __shfl_xor(v.z, 32, 64);
        v.w += __shfl_xor(v.w, 32, 64);
        if ((k & 3) == q) {
            int r = wid * 8 + k;
            int node = n0 + r;
            if (node < n_nodes) {
                int dgt = s_noff[r + 1] - s_noff[r];
                float4 res;
                if (dgt > 0) {
                    float inv = 1.0f / (float)dgt;
                    res = make_float4(v.x * inv, v.y * inv, v.z * inv, v.w * inv);
                } else {
                    uint2 u = *reinterpret_cast<const uint2*>(gm + (size_t)node * D);
                    res = make_float4(blo(u.x), bhi(u.x), blo(u.y), bhi(u.y));
                }
                res.x = fmaxf(res.x + bj.x, 0.0f);
                res.y = fmaxf(res.y + bj.y, 0.0f);
                res.z = fmaxf(res.z + bj.z, 0.0f);
                res.w = fmaxf(res.w + bj.w, 0.0f);
                *reinterpret_cast<float4*>(out + (size_t)node * D + 4 * m) = res;
            }
        }
    }
}

// ---------------- fallback consumer: R10 k_bucket4 (in-block sort) ----------------

__global__ __launch_bounds__(256) void k_bucket4(
    const ushort* __restrict__ g,
    const float* __restrict__ bias,
    const int* __restrict__ base,
    const unsigned* __restrict__ packed,
    float* __restrict__ out,
    int n_nodes, int sbits)
{
    __shared__ unsigned s_raw[CHUNK];
    __shared__ unsigned s_rec[CHUNK];
    __shared__ int s_cnt[SUBN];
    __shared__ int s_off[SUBN + 1];

    int t = threadIdx.x;
    int lane = t & 63;
    int wid  = t >> 6;
    int q = lane >> 4;
    int m = lane & 15;
    int bkt = blockIdx.x >> 2;
    int sub = blockIdx.x & 3;
    int gb = base[bkt], ge = base[bkt + 1];
    unsigned smask = (1u << sbits) - 1u;
    const ushort* gm = g + 4 * m;

    float4 acc[8];
    int degv[8];
    #pragma unroll
    for (int k = 0; k < 8; ++k) {
        acc[k] = make_float4(0.f, 0.f, 0.f, 0.f);
        degv[k] = 0;
    }

    for (int cb = gb; cb < ge; cb += CHUNK) {
        int cnt = ge - cb;
        if (cnt > CHUNK) cnt = CHUNK;
        __syncthreads();
        if (t < SUBN) s_cnt[t] = 0;
        for (int i = t; i < cnt; i += 256) s_raw[i] = packed[cb + i];
        __syncthreads();
        for (int i = t; i < cnt; i += 256) {
            unsigned key = s_raw[i] >> sbits;
            if ((int)(key >> 5) == sub) atomicAdd(&s_cnt[key & 31], 1);
        }
        __syncthreads();
        if (t < 32) {
            int v = s_cnt[t];
            int incl = v;
            #pragma unroll
            for (int o = 1; o < 32; o <<= 1) {
                int u = __shfl_up(incl, o, 64);
                if (t >= o) incl += u;
            }
            int excl = incl - v;
            s_off[t] = excl;
            s_cnt[t] = excl;
            if (t == 31) s_off[32] = incl;
        }
        __syncthreads();
        for (int i = t; i < cnt; i += 256) {
            unsigned v = s_raw[i];
            unsigned key = v >> sbits;
            if ((int)(key >> 5) == sub) {
                int pos = atomicAdd(&s_cnt[key & 31], 1);
                s_rec[pos] = v;
            }
        }
        __syncthreads();
        #pragma unroll
        for (int k = 0; k < 8; ++k) {
            int r = wid * 8 + k;
            int beg = s_off[r], end = s_off[r + 1];
            float4 a = acc[k];
            for (int i = beg; i < end; i += 16) {
                int i0 = i + q, i1 = i0 + 4, i2 = i0 + 8, i3 = i0 + 12;
                bool p0 = i0 < end, p1 = i1 < end, p2 = i2 < end, p3 = i3 < end;
                unsigned r0 = s_rec[p0 ? i0 : beg];
                unsigned r1 = s_rec[p1 ? i1 : beg];
                unsigned r2 = s_rec[p2 ? i2 : beg];
                unsigned r3 = s_rec[p3 ? i3 : beg];
                int s0 = (int)(r0 & smask), s1 = (int)(r1 & smask);
                int s2 = (int)(r2 & smask), s3 = (int)(r3 & smask);
                uint2 u0 = *reinterpret_cast<const uint2*>(gm + (size_t)s0 * D);
                uint2 u1 = *reinterpret_cast<const uint2*>(gm + (size_t)s1 * D);
                uint2 u2 = *reinterpret_cast<const uint2*>(gm + (size_t)s2 * D);
                uint2 u3 = *reinterpret_cast<const uint2*>(gm + (size_t)s3 * D);
                a.x += p0 ? blo(u0.x) : 0.0f;  a.y += p0 ? bhi(u0.x) : 0.0f;
                a.z += p0 ? blo(u0.y) : 0.0f;  a.w += p0 ? bhi(u0.y) : 0.0f;
                a.x += p1 ? blo(u1.x) : 0.0f;  a.y += p1 ? bhi(u1.x) : 0.0f;
                a.z += p1 ? blo(u1.y) : 0.0f;  a.w += p1 ? bhi(u1.y) : 0.0f;
                a.x += p2 ? blo(u2.x) : 0.0f;  a.y += p2 ? bhi(u2.x) : 0.0f;
                a.z += p2 ? blo(u2.y) : 0.0f;  a.w += p2 ? bhi(u2.y) : 0.0f;
                a.x += p3 ? blo(u3.x) : 0.0f;  a.y += p3 ? bhi(u3.x) : 0.0f;
                a.z += p3 ? blo(u3.y) : 0.0f;  a.w += p3 ? bhi(u3.y) : 0.0f;
            }
            acc[k] = a;
            degv[k] += end - beg;
        }
    }

    float4 bj = *reinterpret_cast<const float4*>(bias + 4 * m);
    int n0 = (bkt << LOGB) + sub * SUBN;
    #pragma unroll
    for (int k = 0; k < 8; ++k) {
        float4 v = acc[k];
        v.x += __shfl_xor(v.x, 16, 64);
        v.y += __shfl_xor(v.y, 16, 64);
        v.z += __shfl_xor(v.z, 16, 64);
        v.w += __shfl_xor(v.w, 16, 64);
        v.x += __shfl_xor(v.x, 32, 64);
        v.y += __shfl_xor(v.y, 32, 64);
        v.z += __shfl_xor(v.z, 32, 64);
        v.w += __shfl_xor(v.w, 32, 64);
        if ((k & 3) == q) {
            int node = n0 + wid * 8 + k;
            if (node < n_nodes) {
                int dgt = degv[k];
                float4 res;
                if (dgt > 0) {
                    float inv = 1.0f / (float)dgt;
                    res = make_float4(v.x * inv, v.y * inv, v.z * inv, v.w * inv);
                } else {
                    uint2 u = *reinterpret_cast<const uint2*>(gm + (size_t)node * D);
                    res = make_float4(blo(u.x), bhi(u.x), blo(u.y), bhi(u.y));
                }
                res.x = fmaxf(res.x + bj.x, 0.0f);
                res.y = fmaxf(res.y + bj.y, 0.0f);
                res.z = fmaxf(res.z + bj.z, 0.0f);
                res.w = fmaxf(res.w + bj.w, 0.0f);
                *reinterpret_cast<float4*>(out + (size_t)node * D + 4 * m) = res;
            }
        }
    }
}

// ---------------- host ----------------

extern "C" void kernel_launch(void* const* d_in, const int* in_sizes, int n_in,
                              void* d_out, int out_size, void* d_ws, size_t ws_size,
                              hipStream_t stream)
{
    const float* feat = (const float*)d_in[0];
    const int*   src  = (const int*)d_in[1];
    const int*   dst  = (const int*)d_in[2];
    const float* W    = (const float*)d_in[3];
    const float* b    = (const float*)d_in[4];
    float* out = (float*)d_out;

    int n_nodes = in_sizes[0] / D;
    int n_edges = in_sizes[1];
    int nbkt = (n_nodes + BNODES - 1) >> LOGB;

    int sbits = 1;
    while ((1 << sbits) < n_nodes && sbits < 25) sbits++;

    // ws layout (new): bbase[nbkt+1] | bcnt[nbkt] | bcursor[nbkt] | noff[N+1]
    //                  | packed[E] | csr2[E] | g[(N+1)*64] ushort
    size_t base_off   = 0;
    size_t cnt_off    = (((size_t)(nbkt + 1) * 4) + 63) & ~(size_t)63;
    size_t cursor_off = (cnt_off + (size_t)nbkt * 4 + 63) & ~(size_t)63;
    size_t noff_off   = (cursor_off + (size_t)nbkt * 4 + 63) & ~(size_t)63;
    size_t packed_off = (noff_off + ((size_t)n_nodes + 1) * 4 + 63) & ~(size_t)63;
    size_t csr2_off   = (packed_off + (size_t)n_edges * 4 + 63) & ~(size_t)63;
    size_t g_off      = (csr2_off + (size_t)n_edges * 4 + 63) & ~(size_t)63;
    size_t need_new   = g_off + ((size_t)n_nodes + 1) * D * 2;

    // fallback layout (no csr2/noff): bbase | bcnt | bcursor | packed | g
    size_t o_packed_off = noff_off;
    size_t o_g_off      = (o_packed_off + (size_t)n_edges * 4 + 63) & ~(size_t)63;
    size_t need_old     = o_g_off + ((size_t)n_nodes + 1) * D * 2;

    bool common_ok = (nbkt <= 1024) && (sbits + LOGB <= 32) &&
                     ((1 << sbits) >= n_nodes);
    char* ws = (char*)d_ws;
    int tblk = (n_nodes + TN - 1) / TN;
    int nblk = (n_edges + 4095) / 4096;
    int hb = ((n_edges >> 2) + 4095) / 4096;   // histogram blocks (16 int4/thread)
    bool fuse_hist = (hb <= tblk);

    if (common_ok && ws_size >= need_new) {
        int* bbase   = (int*)(ws + base_off);
        int* bcnt    = (int*)(ws + cnt_off);
        int* bcursor = (int*)(ws + cursor_off);
        int* noff    = (int*)(ws + noff_off);
        unsigned* packed = (unsigned*)(ws + packed_off);
        int* csr2    = (int*)(ws + csr2_off);
        ushort* g    = (ushort*)(ws + g_off);

        hipMemsetAsync(bcnt, 0, (size_t)nbkt * 4, stream);
        k_transform5<<<tblk, 256, 0, stream>>>(feat, W, g, n_nodes, dst, n_edges,
                                               bcnt, nbkt, fuse_hist ? hb : 0);
        if (!fuse_hist)
            k_bin_count<<<512, 256, 0, stream>>>(dst, bcnt, n_edges, nbkt);
        k_bin_scan<<<1, 1024, 0, stream>>>(bcnt, bbase, bcursor, nbkt);
        k_bin_scatter<<<nblk, 256, 0, stream>>>(src, dst, bcursor, packed,
                                                n_edges, sbits);
        k_sort128<<<nbkt, 256, 0, stream>>>(packed, bbase, csr2, noff,
                                            n_nodes, sbits);
        int ngrp6 = (n_nodes + GRP6 - 1) / GRP6;
        k_bucket6<<<ngrp6, 256, 0, stream>>>(g, b, noff, csr2, out, n_nodes);
    } else if (common_ok && ws_size >= need_old) {
        int* bbase   = (int*)(ws + base_off);
        int* bcnt    = (int*)(ws + cnt_off);
        int* bcursor = (int*)(ws + cursor_off);
        unsigned* packed = (unsigned*)(ws + o_packed_off);
        ushort* g    = (ushort*)(ws + o_g_off);

        hipMemsetAsync(bcnt, 0, (size_t)nbkt * 4, stream);
        k_transform5<<<tblk, 256, 0, stream>>>(feat, W, g, n_nodes, dst, n_edges,
                                               bcnt, nbkt, fuse_hist ? hb : 0);
        if (!fuse_hist)
            k_bin_count<<<512, 256, 0, stream>>>(dst, bcnt, n_edges, nbkt);
        k_bin_scan<<<1, 1024, 0, stream>>>(bcnt, bbase, bcursor, nbkt);
        k_bin_scatter<<<nblk, 256, 0, stream>>>(src, dst, bcursor, packed,
                                                n_edges, sbits);
        k_bucket4<<<nbkt * 4, 256, 0, stream>>>(g, b, bbase, packed, out,
                                                n_nodes, sbits);
    }
}

// Round 13
// 100.066 us; speedup vs baseline: 2.4048x; 1.0102x over previous
//
#include <hip/hip_runtime.h>
#include <hip/hip_bf16.h>

#define D 64
#define LOGB 7            // 128 nodes per bin-bucket
#define BNODES 128
#define GRP6 32           // nodes per k_bucket6 block
#define CH6 1024          // record chunk in k_bucket6
#define TN 64             // nodes per transform block

__device__ __forceinline__ float blo(unsigned u) { return __uint_as_float(u << 16); }
__device__ __forceinline__ float bhi(unsigned u) { return __uint_as_float(u & 0xffff0000u); }
__device__ __forceinline__ ushort f2bfr(float x) {
    __hip_bfloat16 hb = __float2bfloat16(x);     // RNE
    return *reinterpret_cast<ushort*>(&hb);
}

// ---------------- k_hist: standalone dst-bucket histogram ----------------

__global__ __launch_bounds__(256) void k_hist(
    const int* __restrict__ dst, int* __restrict__ cnt, int n_edges, int nbkt)
{
    __shared__ int sc[1024];
    int t = threadIdx.x;
    for (int i = t; i < 1024; i += 256) sc[i] = 0;
    __syncthreads();
    int n4 = n_edges >> 2;
    const int4* d4 = (const int4*)dst;
    int stride = gridDim.x * 256;
    for (int i = blockIdx.x * 256 + t; i < n4; i += stride) {
        int4 d = d4[i];
        atomicAdd(&sc[d.x >> LOGB], 1);
        atomicAdd(&sc[d.y >> LOGB], 1);
        atomicAdd(&sc[d.z >> LOGB], 1);
        atomicAdd(&sc[d.w >> LOGB], 1);
    }
    if (blockIdx.x == 0 && t == 0)
        for (int e = n4 << 2; e < n_edges; ++e) atomicAdd(&cnt[dst[e] >> LOGB], 1);
    __syncthreads();
    for (int i = t; i < nbkt; i += 256) {
        int c = sc[i];
        if (c) atomicAdd(&cnt[i], c);
    }
}

// ---------------- k_bin_scan ----------------

__global__ __launch_bounds__(1024) void k_bin_scan(
    const int* __restrict__ cnt, int* __restrict__ base,
    int* __restrict__ cursor, int nbkt)
{
    int t = threadIdx.x;
    int v = (t < nbkt) ? cnt[t] : 0;
    int lane = t & 63;
    int incl = v;
    #pragma unroll
    for (int o = 1; o < 64; o <<= 1) {
        int u = __shfl_up(incl, o, 64);
        if (lane >= o) incl += u;
    }
    __shared__ int wtot[16];
    if (lane == 63) wtot[t >> 6] = incl;
    __syncthreads();
    int wpre = 0;
    int w = t >> 6;
    for (int i = 0; i < w; ++i) wpre += wtot[i];
    int excl = wpre + incl - v;
    if (t < nbkt) { base[t] = excl; cursor[t] = excl; }
    if (t == nbkt - 1) base[nbkt] = excl + v;
}

// ---------------- k_fused: blocks [0,nblk) = bin_scatter; [nblk,..) = transform ----
// Independent chains overlapped in one dispatch. LDS overlaid: scatter 45KB,
// transform 32KB (max 45072B static).

__global__ __launch_bounds__(256) void k_fused(
    // scatter args
    const int* __restrict__ src, const int* __restrict__ dst,
    int* __restrict__ cursor, unsigned* __restrict__ packed,
    int n_edges, int sbits, int nblk,
    // transform args
    const float* __restrict__ feat, const float* __restrict__ W,
    ushort* __restrict__ g, int n_nodes)
{
    __shared__ __align__(16) char smem[45072];
    int t = threadIdx.x;

    if ((int)blockIdx.x < nblk) {
        // ---------------- bin_scatter body ----------------
        int* s_cnt  = (int*)smem;                       // 1024 ints
        int* s_base = (int*)(smem + 4096);              // 1024 ints
        int* s_gb   = (int*)(smem + 8192);              // 1024 ints
        int* wtot   = (int*)(smem + 12288);             // 4 ints
        unsigned* s_stage = (unsigned*)(smem + 12304);  // 4096 u32
        int* s_addr = (int*)(smem + 28688);             // 4096 ints

        int chbase = blockIdx.x * 4096;
        int count = n_edges - chbase;
        if (count > 4096) count = 4096;

        for (int i = t; i < 1024; i += 256) s_cnt[i] = 0;
        __syncthreads();

        #pragma unroll
        for (int k = 0; k < 16; ++k) {
            int i = t + k * 256;
            if (i < count) atomicAdd(&s_cnt[dst[chbase + i] >> LOGB], 1);
        }
        __syncthreads();

        int b4 = t * 4;
        int v0 = s_cnt[b4], v1 = s_cnt[b4 + 1], v2 = s_cnt[b4 + 2], v3 = s_cnt[b4 + 3];
        int ssum = v0 + v1 + v2 + v3;
        int lane = t & 63;
        int incl = ssum;
        #pragma unroll
        for (int o = 1; o < 64; o <<= 1) {
            int u = __shfl_up(incl, o, 64);
            if (lane >= o) incl += u;
        }
        if (lane == 63) wtot[t >> 6] = incl;
        __syncthreads();
        int wpre = 0;
        int w = t >> 6;
        for (int i = 0; i < w; ++i) wpre += wtot[i];
        int excl = wpre + incl - ssum;
        s_base[b4]     = excl;
        s_base[b4 + 1] = excl + v0;
        s_base[b4 + 2] = excl + v0 + v1;
        s_base[b4 + 3] = excl + v0 + v1 + v2;
        __syncthreads();

        for (int i = t; i < 1024; i += 256) {
            int c = s_cnt[i];
            s_gb[i] = c ? atomicAdd(&cursor[i], c) : 0;
        }
        __syncthreads();
        for (int i = t; i < 1024; i += 256) s_cnt[i] = s_base[i];
        __syncthreads();

        #pragma unroll
        for (int k = 0; k < 16; ++k) {
            int i = t + k * 256;
            if (i < count) {
                int e = chbase + i;
                int d = dst[e];
                int s = src[e];
                int bkt = d >> LOGB;
                int pos = atomicAdd(&s_cnt[bkt], 1);
                s_stage[pos] = ((unsigned)(d & (BNODES - 1)) << sbits) | (unsigned)s;
                s_addr[pos]  = s_gb[bkt] + (pos - s_base[bkt]);
            }
        }
        __syncthreads();

        #pragma unroll
        for (int k = 0; k < 16; ++k) {
            int i = t + k * 256;
            if (i < count) packed[s_addr[i]] = s_stage[i];
        }
    } else {
        // ---------------- transform body: g = bf16(feat @ W) ----------------
        float* ft = (float*)smem;            // [k][node] 64*64
        float* Ws = (float*)(smem + 16384);  // [k][j]    64*64

        int bid = blockIdx.x - nblk;
        int n0 = bid * TN;

        // zero sentinel row (row n_nodes)
        if (bid == 0 && t < 64) g[(size_t)n_nodes * D + t] = 0;

        {   // stage W, coalesced
            const float4* W4 = (const float4*)W;
            float4* Ws4 = (float4*)Ws;
            #pragma unroll
            for (int i = 0; i < 4; ++i) Ws4[t + i * 256] = W4[t + i * 256];
        }
        {   // stage feat tile transposed
            const float4* f4 = (const float4*)feat;
            #pragma unroll
            for (int it = 0; it < 4; ++it) {
                int i = it * 256 + t;
                int r = i >> 4, c = i & 15;
                int node = n0 + r;
                float4 v = (node < n_nodes) ? f4[(size_t)node * 16 + c]
                                            : make_float4(0.f, 0.f, 0.f, 0.f);
                ft[(4 * c + 0) * TN + r] = v.x;
                ft[(4 * c + 1) * TN + r] = v.y;
                ft[(4 * c + 2) * TN + r] = v.z;
                ft[(4 * c + 3) * TN + r] = v.w;
            }
        }
        __syncthreads();

        int nq = t >> 4, cq = t & 15;
        int n4 = nq * 4, c4 = cq * 4;

        float4 a0 = make_float4(0.f, 0.f, 0.f, 0.f);
        float4 a1 = a0, a2 = a0, a3 = a0;

        #pragma unroll 16
        for (int k = 0; k < D; ++k) {
            float4 fv = *reinterpret_cast<const float4*>(&ft[k * TN + n4]);
            float4 wv = *reinterpret_cast<const float4*>(&Ws[k * D + c4]);
            a0.x = fmaf(fv.x, wv.x, a0.x); a0.y = fmaf(fv.x, wv.y, a0.y);
            a0.z = fmaf(fv.x, wv.z, a0.z); a0.w = fmaf(fv.x, wv.w, a0.w);
            a1.x = fmaf(fv.y, wv.x, a1.x); a1.y = fmaf(fv.y, wv.y, a1.y);
            a1.z = fmaf(fv.y, wv.z, a1.z); a1.w = fmaf(fv.y, wv.w, a1.w);
            a2.x = fmaf(fv.z, wv.x, a2.x); a2.y = fmaf(fv.z, wv.y, a2.y);
            a2.z = fmaf(fv.z, wv.z, a2.z); a2.w = fmaf(fv.z, wv.w, a2.w);
            a3.x = fmaf(fv.w, wv.x, a3.x); a3.y = fmaf(fv.w, wv.y, a3.y);
            a3.z = fmaf(fv.w, wv.z, a3.z); a3.w = fmaf(fv.w, wv.w, a3.w);
        }

        float4 accs[4] = {a0, a1, a2, a3};
        #pragma unroll
        for (int i = 0; i < 4; ++i) {
            int node = n0 + n4 + i;
            if (node < n_nodes) {
                ushort4 o;
                o.x = f2bfr(accs[i].x);
                o.y = f2bfr(accs[i].y);
                o.z = f2bfr(accs[i].z);
                o.w = f2bfr(accs[i].w);
                *reinterpret_cast<ushort4*>(g + (size_t)node * D + c4) = o;
            }
        }
    }
}

// ---------------- k_sort128: per-bucket full node sort -> csr2 + noff ----------------

__global__ __launch_bounds__(256) void k_sort128(
    const unsigned* __restrict__ packed,
    const int* __restrict__ bbase,
    int* __restrict__ csr2,
    int* __restrict__ noff,
    int n_nodes, int sbits)
{
    __shared__ int s_cnt[BNODES];
    __shared__ int s_off[BNODES + 1];

    int t = threadIdx.x;
    int b = blockIdx.x;
    int gb = bbase[b], cnt = bbase[b + 1] - gb;

    if (t < BNODES) s_cnt[t] = 0;
    __syncthreads();
    for (int i = t; i < cnt; i += 256)
        atomicAdd(&s_cnt[packed[gb + i] >> sbits], 1);
    __syncthreads();

    if (t < 64) {
        int v0 = s_cnt[2 * t], v1 = s_cnt[2 * t + 1];
        int s = v0 + v1, incl = s;
        #pragma unroll
        for (int o = 1; o < 64; o <<= 1) {
            int u = __shfl_up(incl, o, 64);
            if (t >= o) incl += u;
        }
        int excl = incl - s;
        s_off[2 * t] = excl;
        s_off[2 * t + 1] = excl + v0;
        if (t == 63) s_off[BNODES] = incl;
    }
    __syncthreads();

    if (t <= BNODES) {
        int node = b * BNODES + t;
        if (node <= n_nodes) noff[node] = gb + s_off[t];
    }
    if (t < BNODES) s_cnt[t] = s_off[t];
    __syncthreads();

    unsigned smask = (1u << sbits) - 1u;
    for (int i = t; i < cnt; i += 256) {
        unsigned v = packed[gb + i];
        int pos = atomicAdd(&s_cnt[v >> sbits], 1);
        csr2[gb + pos] = (int)(v & smask);
    }
}

// ---------------- k_bucket6: 32-node blocks over globally-sorted csr2 ----------------

__global__ __launch_bounds__(256) void k_bucket6(
    const ushort* __restrict__ g,      // [(N+1)][64], row N = zeros
    const float* __restrict__ bias,
    const int* __restrict__ noff,      // [N+1]
    const int* __restrict__ csr2,      // [E] srcs sorted by dst
    float* __restrict__ out, int n_nodes)
{
    __shared__ int s_src[CH6];
    __shared__ int s_noff[GRP6 + 1];

    int t = threadIdx.x;
    int n0 = blockIdx.x * GRP6;
    if (t <= GRP6) {
        int node = n0 + t;
        s_noff[t] = noff[node > n_nodes ? n_nodes : node];
    }
    __syncthreads();

    int lane = t & 63, wid = t >> 6;
    int q = lane >> 4;                 // record slot 0..3
    int m = lane & 15;                 // features 4m..4m+3
    const ushort* gm = g + 4 * m;

    float4 acc[8];
    #pragma unroll
    for (int k = 0; k < 8; ++k) acc[k] = make_float4(0.f, 0.f, 0.f, 0.f);

    int beg = s_noff[0], end = s_noff[GRP6];
    for (int cb = beg; cb < end; cb += CH6) {
        int ce = cb + CH6 < end ? cb + CH6 : end;
        __syncthreads();               // protect s_src from previous chunk
        for (int i = cb + t; i < ce; i += 256) s_src[i - cb] = csr2[i];
        __syncthreads();

        #pragma unroll
        for (int k = 0; k < 8; ++k) {
            int r = wid * 8 + k;
            int lo = s_noff[r], hi = s_noff[r + 1];
            if (lo < cb) lo = cb;
            if (hi > ce) hi = ce;
            float4 a = acc[k];
            for (int i = lo; i < hi; i += 16) {
                int i0 = i + q, i1 = i0 + 4, i2 = i0 + 8, i3 = i0 + 12;
                int s0 = (i0 < hi) ? s_src[i0 - cb] : n_nodes;
                int s1 = (i1 < hi) ? s_src[i1 - cb] : n_nodes;
                int s2 = (i2 < hi) ? s_src[i2 - cb] : n_nodes;
                int s3 = (i3 < hi) ? s_src[i3 - cb] : n_nodes;
                uint2 u0 = *reinterpret_cast<const uint2*>(gm + (size_t)s0 * D);
                uint2 u1 = *reinterpret_cast<const uint2*>(gm + (size_t)s1 * D);
                uint2 u2 = *reinterpret_cast<const uint2*>(gm + (size_t)s2 * D);
                uint2 u3 = *reinterpret_cast<const uint2*>(gm + (size_t)s3 * D);
                a.x += blo(u0.x); a.y += bhi(u0.x); a.z += blo(u0.y); a.w += bhi(u0.y);
                a.x += blo(u1.x); a.y += bhi(u1.x); a.z += blo(u1.y); a.w += bhi(u1.y);
                a.x += blo(u2.x); a.y += bhi(u2.x); a.z += blo(u2.y); a.w += bhi(u2.y);
                a.x += blo(u3.x); a.y += bhi(u3.x); a.z += blo(u3.y); a.w += bhi(u3.y);
            }
            acc[k] = a;
        }
    }

    float4 bj = *reinterpret_cast<const float4*>(bias + 4 * m);
    #pragma unroll
    for (int k = 0; k < 8; ++k) {
        float4 v = acc[k];
        v.x += __shfl_xor(v.x, 16, 64);
        v.y += __shfl_xor(v.y, 16, 64);
        v.z += __shfl_xor(v.z, 16, 64);
        v.w += __shfl_xor(v.w, 16, 64);
        v.x += __shfl_xor(v.x, 32, 64);
        v.y += __shfl_xor(v.y, 32, 64);
        v.z += __shfl_xor(v.z, 32, 64);
        v.w += __shfl_xor(v.w, 32, 64);
        if ((k & 3) == q) {
            int r = wid * 8 + k;
            int node = n0 + r;
            if (node < n_nodes) {
                int dgt = s_noff[r + 1] - s_noff[r];
                float4 res;
                if (dgt > 0) {
                    float inv = 1.0f / (float)dgt;
                    res = make_float4(v.x * inv, v.y * inv, v.z * inv, v.w * inv);
                } else {
                    uint2 u = *reinterpret_cast<const uint2*>(gm + (size_t)node * D);
                    res = make_float4(blo(u.x), bhi(u.x), blo(u.y), bhi(u.y));
                }
                res.x = fmaxf(res.x + bj.x, 0.0f);
                res.y = fmaxf(res.y + bj.y, 0.0f);
                res.z = fmaxf(res.z + bj.z, 0.0f);
                res.w = fmaxf(res.w + bj.w, 0.0f);
                *reinterpret_cast<float4*>(out + (size_t)node * D + 4 * m) = res;
            }
        }
    }
}

// ---------------- host ----------------

extern "C" void kernel_launch(void* const* d_in, const int* in_sizes, int n_in,
                              void* d_out, int out_size, void* d_ws, size_t ws_size,
                              hipStream_t stream)
{
    const float* feat = (const float*)d_in[0];
    const int*   src  = (const int*)d_in[1];
    const int*   dst  = (const int*)d_in[2];
    const float* W    = (const float*)d_in[3];
    const float* b    = (const float*)d_in[4];
    float* out = (float*)d_out;

    int n_nodes = in_sizes[0] / D;
    int n_edges = in_sizes[1];
    int nbkt = (n_nodes + BNODES - 1) >> LOGB;

    int sbits = 1;
    while ((1 << sbits) < n_nodes && sbits < 25) sbits++;

    // ws layout: bbase[nbkt+1] | bcnt[nbkt] | bcursor[nbkt] | noff[N+1]
    //            | packed[E] | csr2[E] | g[(N+1)*64] ushort
    size_t base_off   = 0;
    size_t cnt_off    = (((size_t)(nbkt + 1) * 4) + 63) & ~(size_t)63;
    size_t cursor_off = (cnt_off + (size_t)nbkt * 4 + 63) & ~(size_t)63;
    size_t noff_off   = (cursor_off + (size_t)nbkt * 4 + 63) & ~(size_t)63;
    size_t packed_off = (noff_off + ((size_t)n_nodes + 1) * 4 + 63) & ~(size_t)63;
    size_t csr2_off   = (packed_off + (size_t)n_edges * 4 + 63) & ~(size_t)63;
    size_t g_off      = (csr2_off + (size_t)n_edges * 4 + 63) & ~(size_t)63;
    size_t need       = g_off + ((size_t)n_nodes + 1) * D * 2;

    bool ok = (ws_size >= need) && (nbkt <= 1024) && (sbits + LOGB <= 32) &&
              ((1 << sbits) >= n_nodes);
    if (!ok) return;   // cannot happen for this problem's shapes

    char* ws = (char*)d_ws;
    int* bbase   = (int*)(ws + base_off);
    int* bcnt    = (int*)(ws + cnt_off);
    int* bcursor = (int*)(ws + cursor_off);
    int* noff    = (int*)(ws + noff_off);
    unsigned* packed = (unsigned*)(ws + packed_off);
    int* csr2    = (int*)(ws + csr2_off);
    ushort* g    = (ushort*)(ws + g_off);

    int tblk = (n_nodes + TN - 1) / TN;
    int nblk = (n_edges + 4095) / 4096;

    hipMemsetAsync(bcnt, 0, (size_t)nbkt * 4, stream);
    k_hist<<<256, 256, 0, stream>>>(dst, bcnt, n_edges, nbkt);
    k_bin_scan<<<1, 1024, 0, stream>>>(bcnt, bbase, bcursor, nbkt);
    k_fused<<<nblk + tblk, 256, 0, stream>>>(src, dst, bcursor, packed,
                                             n_edges, sbits, nblk,
                                             feat, W, g, n_nodes);
    k_sort128<<<nbkt, 256, 0, stream>>>(packed, bbase, csr2, noff,
                                        n_nodes, sbits);
    int ngrp6 = (n_nodes + GRP6 - 1) / GRP6;
    k_bucket6<<<ngrp6, 256, 0, stream>>>(g, b, noff, csr2, out, n_nodes);
}